// Round 1
// baseline (196.674 us; speedup 1.0000x reference)
//
#include <hip/hip_runtime.h>
#include <math.h>

// One block per (batch row, long/short). 256 threads = 4 waves.
// 16 lanes cooperate on one sequence row (16 x float4 = 64 floats),
// so each wave loads 4 contiguous rows = 1KB fully coalesced.
__global__ __launch_bounds__(256) void cosine_simtier_kernel(
    const float* __restrict__ item,                                   // [B,64]
    const float* __restrict__ seqL, const int* __restrict__ indL, const float* __restrict__ embL,
    const float* __restrict__ seqS, const int* __restrict__ indS, const float* __restrict__ embS,
    float* __restrict__ cosL, float* __restrict__ cosS,
    float* __restrict__ stL,  float* __restrict__ stS,
    int B, int SL, int SS, int nbL, int nbS)
{
    const bool isLong = ((int)blockIdx.x) < B;
    const int b   = isLong ? (int)blockIdx.x : (int)blockIdx.x - B;
    const int S   = isLong ? SL : SS;
    const int nb  = isLong ? nbL : nbS;
    const int bias = (nb - 2) / 2;            // 22 -> 10, 42 -> 20
    const float scale = (float)bias;          // exactly 1/eps (10.0, 20.0)
    const float* __restrict__ seq = isLong ? seqL : seqS;
    const int*   __restrict__ ind = isLong ? indL : indS;
    const float* __restrict__ emb = isLong ? embL : embS;
    float* __restrict__ cosOut = isLong ? cosL : cosS;
    float* __restrict__ stOut  = isLong ? stL  : stS;

    const int tid = threadIdx.x;
    __shared__ float item_n[64];
    __shared__ int   hist[64];

    // Normalize item row (wave 0 only), zero histogram.
    if (tid < 64) {
        float v = item[(size_t)b * 64 + tid];
        float sq = v * v;
        #pragma unroll
        for (int off = 32; off >= 1; off >>= 1)
            sq += __shfl_xor(sq, off, 64);
        item_n[tid] = v * (1.0f / (sqrtf(sq) + 1e-8f));
        hist[tid] = 0;
    }
    __syncthreads();

    const int sub      = tid & 15;   // float4 index within row
    const int rowInBlk = tid >> 4;   // 0..15
    const float ia0 = item_n[sub * 4 + 0];
    const float ia1 = item_n[sub * 4 + 1];
    const float ia2 = item_n[sub * 4 + 2];
    const float ia3 = item_n[sub * 4 + 3];

    const float4* __restrict__ seqb = reinterpret_cast<const float4*>(seq) + (size_t)b * S * 16;
    const int*    __restrict__ indb = ind    + (size_t)b * S;
    float*        __restrict__ cosb = cosOut + (size_t)b * S;

    for (int base = 0; base < S; base += 16) {
        const int r = base + rowInBlk;
        const float4 v = seqb[(size_t)r * 16 + sub];
        float dot = ia0 * v.x + ia1 * v.y + ia2 * v.z + ia3 * v.w;
        float sq  = v.x * v.x + v.y * v.y + v.z * v.z + v.w * v.w;
        // reduce across the 16-lane group
        #pragma unroll
        for (int off = 8; off >= 1; off >>= 1) {
            dot += __shfl_xor(dot, off, 64);
            sq  += __shfl_xor(sq,  off, 64);
        }
        if (sub == 0) {
            float cosv = dot / (sqrtf(sq) + 1e-8f);
            if (indb[r] <= 0) cosv = -2.0f;
            cosb[r] = cosv;
            const int id = (int)ceilf(cosv * scale) + bias;
            if (id >= 0 && id < nb) atomicAdd(&hist[id], 1);
        }
    }
    __syncthreads();

    // Epilogue: st[b, id*8+j] = log(count+1) * emb[id*8+j]
    const int nout = nb * 8;
    for (int t = tid; t < nout; t += 256) {
        const float c = (float)hist[t >> 3];
        stOut[(size_t)b * nout + t] = logf(c + 1.0f) * emb[t];
    }
}

extern "C" void kernel_launch(void* const* d_in, const int* in_sizes, int n_in,
                              void* d_out, int out_size, void* d_ws, size_t ws_size,
                              hipStream_t stream) {
    const float* item = (const float*)d_in[0];
    const float* seqL = (const float*)d_in[1];
    const float* seqS = (const float*)d_in[2];
    const int*   indL = (const int*)d_in[3];
    const int*   indS = (const int*)d_in[4];
    const float* embL = (const float*)d_in[5];
    const float* embS = (const float*)d_in[6];

    const int B   = in_sizes[0] / 64;
    const int SL  = in_sizes[1] / (B * 64);
    const int SS  = in_sizes[2] / (B * 64);
    const int nbL = in_sizes[5] / 8;   // 22
    const int nbS = in_sizes[6] / 8;   // 42

    float* out  = (float*)d_out;
    float* cosL = out;
    float* cosS = cosL + (size_t)B * SL;
    float* stL  = cosS + (size_t)B * SS;
    float* stS  = stL  + (size_t)B * nbL * 8;

    dim3 grid(2 * B), block(256);
    hipLaunchKernelGGL(cosine_simtier_kernel, grid, block, 0, stream,
                       item, seqL, indL, embL, seqS, indS, embS,
                       cosL, cosS, stL, stS, B, SL, SS, nbL, nbS);
}

// Round 2
// 154.173 us; speedup vs baseline: 1.2757x; 1.2757x over previous
//
#include <hip/hip_runtime.h>
#include <math.h>

// One block per (batch row, long/short). 256 threads = 4 waves.
// 16 lanes cooperate on one sequence row (16 x float4 = 64 floats).
// Unrolled x4: each thread keeps 4 independent float4 loads in flight
// (4 KB per wave) so HBM latency is hidden by MLP, not just wave count.
__global__ __launch_bounds__(256, 8) void cosine_simtier_kernel(
    const float* __restrict__ item,                                   // [B,64]
    const float* __restrict__ seqL, const int* __restrict__ indL, const float* __restrict__ embL,
    const float* __restrict__ seqS, const int* __restrict__ indS, const float* __restrict__ embS,
    float* __restrict__ cosL, float* __restrict__ cosS,
    float* __restrict__ stL,  float* __restrict__ stS,
    int B, int SL, int SS, int nbL, int nbS)
{
    const bool isLong = ((int)blockIdx.x) < B;
    const int b   = isLong ? (int)blockIdx.x : (int)blockIdx.x - B;
    const int S   = isLong ? SL : SS;
    const int nb  = isLong ? nbL : nbS;
    const int bias = (nb - 2) / 2;            // 22 -> 10, 42 -> 20
    const float scale = (float)bias;          // exactly 1/eps (10.0, 20.0)
    const float* __restrict__ seq = isLong ? seqL : seqS;
    const int*   __restrict__ ind = isLong ? indL : indS;
    const float* __restrict__ emb = isLong ? embL : embS;
    float* __restrict__ cosOut = isLong ? cosL : cosS;
    float* __restrict__ stOut  = isLong ? stL  : stS;

    const int tid = threadIdx.x;
    __shared__ float item_n[64];
    __shared__ int   hist[64];

    // Normalize item row (one wave), zero histogram.
    if (tid < 64) {
        float v = item[(size_t)b * 64 + tid];
        float sq = v * v;
        #pragma unroll
        for (int off = 32; off >= 1; off >>= 1)
            sq += __shfl_xor(sq, off, 64);
        item_n[tid] = v * (1.0f / (sqrtf(sq) + 1e-8f));
        hist[tid] = 0;
    }
    __syncthreads();

    const int sub      = tid & 15;   // float4 index within row
    const int rowInBlk = tid >> 4;   // 0..15
    const float ia0 = item_n[sub * 4 + 0];
    const float ia1 = item_n[sub * 4 + 1];
    const float ia2 = item_n[sub * 4 + 2];
    const float ia3 = item_n[sub * 4 + 3];

    const float4* __restrict__ seqb = reinterpret_cast<const float4*>(seq) + (size_t)b * S * 16;
    const int*    __restrict__ indb = ind    + (size_t)b * S;
    float*        __restrict__ cosb = cosOut + (size_t)b * S;

    // 64 rows per block iteration (16 rows x unroll 4). S is 2048 or 512,
    // both divisible by 64.
    for (int base = 0; base < S; base += 64) {
        const int r0 = base + rowInBlk;
        float4 v0 = seqb[(size_t)(r0 +  0) * 16 + sub];
        float4 v1 = seqb[(size_t)(r0 + 16) * 16 + sub];
        float4 v2 = seqb[(size_t)(r0 + 32) * 16 + sub];
        float4 v3 = seqb[(size_t)(r0 + 48) * 16 + sub];

        float dot[4], sq[4];
        dot[0] = ia0*v0.x + ia1*v0.y + ia2*v0.z + ia3*v0.w;
        sq[0]  = v0.x*v0.x + v0.y*v0.y + v0.z*v0.z + v0.w*v0.w;
        dot[1] = ia0*v1.x + ia1*v1.y + ia2*v1.z + ia3*v1.w;
        sq[1]  = v1.x*v1.x + v1.y*v1.y + v1.z*v1.z + v1.w*v1.w;
        dot[2] = ia0*v2.x + ia1*v2.y + ia2*v2.z + ia3*v2.w;
        sq[2]  = v2.x*v2.x + v2.y*v2.y + v2.z*v2.z + v2.w*v2.w;
        dot[3] = ia0*v3.x + ia1*v3.y + ia2*v3.z + ia3*v3.w;
        sq[3]  = v3.x*v3.x + v3.y*v3.y + v3.z*v3.z + v3.w*v3.w;

        // 4 independent reduce chains; shuffle latency overlaps across k.
        #pragma unroll
        for (int off = 8; off >= 1; off >>= 1) {
            #pragma unroll
            for (int k = 0; k < 4; ++k) {
                dot[k] += __shfl_xor(dot[k], off, 64);
                sq[k]  += __shfl_xor(sq[k],  off, 64);
            }
        }

        if (sub == 0) {
            #pragma unroll
            for (int k = 0; k < 4; ++k) {
                const int r = r0 + k * 16;
                float cosv = dot[k] / (sqrtf(sq[k]) + 1e-8f);
                if (indb[r] <= 0) cosv = -2.0f;
                cosb[r] = cosv;
                const int id = (int)ceilf(cosv * scale) + bias;
                if (id >= 0 && id < nb) atomicAdd(&hist[id], 1);
            }
        }
    }
    __syncthreads();

    // Epilogue: st[b, id*8+j] = log(count+1) * emb[id*8+j]
    const int nout = nb * 8;
    for (int t = tid; t < nout; t += 256) {
        const float c = (float)hist[t >> 3];
        stOut[(size_t)b * nout + t] = logf(c + 1.0f) * emb[t];
    }
}

extern "C" void kernel_launch(void* const* d_in, const int* in_sizes, int n_in,
                              void* d_out, int out_size, void* d_ws, size_t ws_size,
                              hipStream_t stream) {
    const float* item = (const float*)d_in[0];
    const float* seqL = (const float*)d_in[1];
    const float* seqS = (const float*)d_in[2];
    const int*   indL = (const int*)d_in[3];
    const int*   indS = (const int*)d_in[4];
    const float* embL = (const float*)d_in[5];
    const float* embS = (const float*)d_in[6];

    const int B   = in_sizes[0] / 64;
    const int SL  = in_sizes[1] / (B * 64);
    const int SS  = in_sizes[2] / (B * 64);
    const int nbL = in_sizes[5] / 8;   // 22
    const int nbS = in_sizes[6] / 8;   // 42

    float* out  = (float*)d_out;
    float* cosL = out;
    float* cosS = cosL + (size_t)B * SL;
    float* stL  = cosS + (size_t)B * SS;
    float* stS  = stL  + (size_t)B * nbL * 8;

    dim3 grid(2 * B), block(256);
    hipLaunchKernelGGL(cosine_simtier_kernel, grid, block, 0, stream,
                       item, seqL, indL, embL, seqS, indS, embS,
                       cosL, cosS, stL, stS, B, SL, SS, nbL, nbS);
}